// Round 16
// baseline (526.186 us; speedup 1.0000x reference)
//
#include <hip/hip_runtime.h>
#include <math.h>
#include <float.h>

// DeepSeek V3 router, round 16.
// R15's scale-free 3-pass numerics PASSED but spilled (96 B-regs + temps >
// 256 budget -> 721MB scratch WRITE_SIZE). R16 keeps the numerics, fixes the
// register plan:
//   pass1 mfma_f16 : fp16(x)        x fp16(256w)          (b0)
//   pass2 mfma_bf16: bf16(x-fp16x)  x bf16(fp16(256w))    (b1 DERIVED from b0)
//   pass3 mfma_bf16: bf16(fp16x)    x bf16(256w-fp16w)    (b3, JIT L2 load)
// B stored as 2 planes only; b1 derived in-register at step start (VALU off
// the MFMA path); b3 loaded just-in-time (issue order b3 -> X -> b0next so
// the b3 wait leaves X/b0next in flight). Live regs ~209: acc64 + A48 +
// B64 (b0 E/O + b1 + b3) + misc. 24 PURE MFMAs per K32, zero in-cluster VALU.
// Skeleton validated R9-R15: 64Mx256N, 4 waves, A swizzled LDS dbuf,
// splitK=4 grid 512, ks=XCD-pinned L2 slices.

#define TDIM 8192
#define DDIM 7168
#define EDIM 256
#define KT   (DDIM / 32)   // 224 k-tiles of 32

typedef _Float16 h8 __attribute__((ext_vector_type(8)));
typedef short    s8 __attribute__((ext_vector_type(8)));
typedef float  f16v __attribute__((ext_vector_type(16)));

#define PSTR ((size_t)8 * KT * 2 * 512)   // B plane stride, 16-bit units

__device__ __forceinline__ short bf16r(float f) {
    unsigned u = __float_as_uint(f);
    u += 0x7FFFu + ((u >> 16) & 1u);   // RNE
    return (short)(u >> 16);
}

// ---------------- K1: W -> 2 fragment-packed planes ------------------------
// p=0: fp16(256w); p=1: bf16(256w - fp16(256w)).
// Record offset (16-bit units) = ((cf*KT+ktl)*2+kf)*512 + lane*8 (+ p*PSTR),
// lane = (e&31) + 32*((k>>3)&1)   [fragment layout validated R9-R15].
__global__ __launch_bounds__(256)
void convert_w(const float* __restrict__ W, short* __restrict__ Bp)
{
    __shared__ _Float16 l0[64][80];
    __shared__ short    l1[64][80];
    const int t = threadIdx.x;
    const int kt = blockIdx.x * 64;
    const int et = blockIdx.y * 64;
#pragma unroll
    for (int i = 0; i < 16; ++i) {
        const int kr = (t >> 6) * 16 + i;
        const int ec = t & 63;
        const float wf = W[(size_t)(kt + kr) * EDIM + et + ec] * 256.f;
        const _Float16 h0 = (_Float16)wf;
        l0[ec][kr] = h0;
        l1[ec][kr] = bf16r(wf - (float)h0);
    }
    __syncthreads();
#pragma unroll
    for (int j = 0; j < 2; ++j) {
        const int er = t >> 2;
        const int kc = ((t & 3) + 4 * j) * 8;
        const int e  = et + er;
        const int k  = kt + kc;
        const int cf   = e >> 5;
        const int lane = (e & 31) + 32 * ((k >> 3) & 1);
        const int kf   = (k >> 4) & 1;
        const int ktl  = k >> 5;
        const uint4 v0 = *(const uint4*)&l0[er][kc];
        const uint4 v1 = *(const uint4*)&l1[er][kc];
        const size_t rb = (((size_t)cf * KT + ktl) * 2 + kf) * 512 + lane * 8;
        *(uint4*)&Bp[rb]        = v0;
        *(uint4*)&Bp[rb + PSTR] = v1;
    }
}

// ---- K2: scale-free 3-pass GEMM, spill-proof register plan ----------------
__global__ __launch_bounds__(256, 2)
void gemm_mfma(const float* __restrict__ X,
               const short* __restrict__ Bp,
               float* __restrict__ P,
               int splitK, int kLen)
{
    __shared__ _Float16 sA0[2][64][32];   // fp16(x), 8 KB
    __shared__ short    sA1[2][64][32];   // bf16(x - fp16(x)), 8 KB

    const int t    = threadIdx.x;
    const int lane = t & 63;
    const int w    = t >> 6;              // wave -> n-quadrant w*64

    const int bid  = blockIdx.x;
    const int ks   = (bid & 7) % splitK;
    const int mb   = (bid >> 3) * (8 / splitK) + (bid & 7) / splitK;
    const int m0   = mb * 64;
    const int kbeg = ks * kLen;
    const int nt   = kLen >> 5;           // 56 steps
    const int ktg0 = kbeg >> 5;

    f16v acc[2][2];
#pragma unroll
    for (int m = 0; m < 2; ++m)
#pragma unroll
        for (int n = 0; n < 2; ++n) acc[m][n] = (f16v)0.f;

    // A staging: thread -> row t>>2 (0..63), granule t&3 (8 floats)
    const int rowA  = t >> 2;
    const int gA    = t & 3;
    const float* xg = X + (size_t)(m0 + rowA) * DDIM + kbeg + gA * 8;
    const int slotA = (gA ^ ((rowA >> 2) & 3)) * 8;   // validated swizzle (R9)

    const short* bb = Bp + lane * 8;

    float4 va0, va1;

#define LOADA(kb)                                                             \
    {                                                                         \
        va0 = *(const float4*)(xg + (kb));                                    \
        va1 = *(const float4*)(xg + (kb) + 4);                                \
    }

#define WRITEA(buf)                                                           \
    {                                                                         \
        h8 p0; s8 p1;                                                         \
        const float xv[8] = {va0.x, va0.y, va0.z, va0.w,                      \
                             va1.x, va1.y, va1.z, va1.w};                     \
        _Pragma("unroll")                                                     \
        for (int q = 0; q < 8; ++q) {                                         \
            const _Float16 h0 = (_Float16)xv[q];                              \
            p0[q] = h0;                                                       \
            p1[q] = bf16r(xv[q] - (float)h0);                                 \
        }                                                                     \
        *(h8*)&sA0[buf][rowA][slotA] = p0;                                    \
        *(s8*)&sA1[buf][rowA][slotA] = p1;                                    \
    }

#define BLOAD0(RB, S)                                                         \
    {                                                                         \
        _Pragma("unroll")                                                     \
        for (int n = 0; n < 2; ++n)                                           \
        _Pragma("unroll")                                                     \
        for (int kf = 0; kf < 2; ++kf)                                        \
            RB[n][kf] = *(const h8*)(bb +                                     \
                (((size_t)(w * 2 + n) * KT + ktg0 + (S)) * 2 + kf) * 512);    \
    }

#define BLOAD3(RB, S)                                                         \
    {                                                                         \
        _Pragma("unroll")                                                     \
        for (int n = 0; n < 2; ++n)                                           \
        _Pragma("unroll")                                                     \
        for (int kf = 0; kf < 2; ++kf)                                        \
            RB[n][kf] = *(const s8*)(bb + PSTR +                              \
                (((size_t)(w * 2 + n) * KT + ktg0 + (S)) * 2 + kf) * 512);    \
    }

#define DERIVE1(B1, B0)                                                       \
    {                                                                         \
        _Pragma("unroll")                                                     \
        for (int n = 0; n < 2; ++n)                                           \
        _Pragma("unroll")                                                     \
        for (int kf = 0; kf < 2; ++kf)                                        \
        _Pragma("unroll")                                                     \
        for (int q = 0; q < 8; ++q)                                           \
            B1[n][kf][q] = bf16r((float)B0[n][kf][q]);                        \
    }

#define AREADCONV(CUR)                                                        \
    {                                                                         \
        _Pragma("unroll")                                                     \
        for (int m = 0; m < 2; ++m)                                           \
        _Pragma("unroll")                                                     \
        for (int kf = 0; kf < 2; ++kf) {                                      \
            const int rr = m * 32 + (lane & 31);                              \
            const int sl = (((lane >> 5) + 2 * kf) ^ ((rr >> 2) & 3)) * 8;    \
            a0h[m][kf] = *(const h8*)&sA0[CUR][rr][sl];                       \
            a1b[m][kf] = *(const s8*)&sA1[CUR][rr][sl];                       \
        }                                                                     \
        _Pragma("unroll")                                                     \
        for (int m = 0; m < 2; ++m)                                           \
        _Pragma("unroll")                                                     \
        for (int kf = 0; kf < 2; ++kf)                                        \
        _Pragma("unroll")                                                     \
        for (int q = 0; q < 8; ++q)                                           \
            a0b[m][kf][q] = bf16r((float)a0h[m][kf][q]);                      \
    }

    // 24 pure MFMAs, zero interleaved VALU
#define MFMA24(B0, B1, B3)                                                    \
    {                                                                         \
        __builtin_amdgcn_s_setprio(1);                                        \
        _Pragma("unroll")                                                     \
        for (int kf = 0; kf < 2; ++kf)                                        \
        _Pragma("unroll")                                                     \
        for (int m = 0; m < 2; ++m)                                           \
        _Pragma("unroll")                                                     \
        for (int n = 0; n < 2; ++n)                                           \
            acc[m][n] = __builtin_amdgcn_mfma_f32_32x32x16_f16(               \
                a0h[m][kf], B0[n][kf], acc[m][n], 0, 0, 0);                   \
        _Pragma("unroll")                                                     \
        for (int kf = 0; kf < 2; ++kf)                                        \
        _Pragma("unroll")                                                     \
        for (int m = 0; m < 2; ++m)                                           \
        _Pragma("unroll")                                                     \
        for (int n = 0; n < 2; ++n)                                           \
            acc[m][n] = __builtin_amdgcn_mfma_f32_32x32x16_bf16(              \
                a1b[m][kf], B1[n][kf], acc[m][n], 0, 0, 0);                   \
        _Pragma("unroll")                                                     \
        for (int kf = 0; kf < 2; ++kf)                                        \
        _Pragma("unroll")                                                     \
        for (int m = 0; m < 2; ++m)                                           \
        _Pragma("unroll")                                                     \
        for (int n = 0; n < 2; ++n)                                           \
            acc[m][n] = __builtin_amdgcn_mfma_f32_32x32x16_bf16(              \
                a0b[m][kf], B3[n][kf], acc[m][n], 0, 0, 0);                   \
        __builtin_amdgcn_s_setprio(0);                                        \
    }

    h8 b0E[2][2], b0O[2][2];

    // ---- prologue: A(0)->buf0; b0(0)->E ----
    LOADA(0);
    BLOAD0(b0E, 0);
    WRITEA(0);
    asm volatile("s_waitcnt lgkmcnt(0)" ::: "memory");
    __builtin_amdgcn_s_barrier();

    for (int ti = 0; ti < nt; ti += 2) {
        {   // even: tile ti from sA[0], b0E
            h8 a0h[2][2]; s8 a1b[2][2], a0b[2][2], b1[2][2], b3[2][2];
            const bool hn = (ti + 1) < nt;
            BLOAD3(b3, ti);                 // JIT (oldest B entry this step)
            if (hn) LOADA((ti + 1) * 32);
            AREADCONV(0);
            DERIVE1(b1, b0E);
            if (hn) BLOAD0(b0O, ti + 1);    // newest -> survives b3 wait
            MFMA24(b0E, b1, b3);
            if (hn) WRITEA(1);
            asm volatile("s_waitcnt lgkmcnt(0)" ::: "memory");
            __builtin_amdgcn_s_barrier();
        }
        {   // odd: tile ti+1 from sA[1], b0O
            h8 a0h[2][2]; s8 a1b[2][2], a0b[2][2], b1[2][2], b3[2][2];
            const bool hp = (ti + 1) < nt;
            const bool hn = (ti + 2) < nt;
            if (hp) BLOAD3(b3, ti + 1);
            if (hn) LOADA((ti + 2) * 32);
            if (hp) { AREADCONV(1); DERIVE1(b1, b0O); }
            if (hn) BLOAD0(b0E, ti + 2);
            if (hp) MFMA24(b0O, b1, b3);
            if (hn) WRITEA(0);
            asm volatile("s_waitcnt lgkmcnt(0)" ::: "memory");
            __builtin_amdgcn_s_barrier();
        }
    }

    // epilogue: logit = acc/256; C/D col=lane&31, row=(r&3)+8*(r>>2)+4*(lane>>5)
    const float s0 = 1.f / 256.f;
#pragma unroll
    for (int m = 0; m < 2; ++m)
#pragma unroll
        for (int n = 0; n < 2; ++n)
#pragma unroll
            for (int r = 0; r < 16; ++r) {
                const int row = (r & 3) + 8 * (r >> 2) + 4 * (lane >> 5);
                const int gr  = m0 + m * 32 + row;
                const int gc  = w * 64 + n * 32 + (lane & 31);
                P[((size_t)ks * TDIM + gr) * EDIM + gc] = acc[m][n][r] * s0;
            }
}

// ---------------- K3: reduce + sigmoid + grouped top-k route ----------------
__global__ __launch_bounds__(256, 4)
void route_kernel(const float* __restrict__ P,
                  const float* __restrict__ B,
                  float* __restrict__ out,
                  int splitK)
{
    const int t    = threadIdx.x;
    const int lane = t & 63;
    const int wid  = t >> 6;
    const int tok0 = blockIdx.x * 32 + wid * 8;

    const float4 bv4 = *(const float4*)&B[lane * 4];
    const float bb[4] = {bv4.x, bv4.y, bv4.z, bv4.w};
    const int g = lane >> 3;

#pragma unroll
    for (int i = 0; i < 8; ++i) {
        const int tok = tok0 + i;
        float a[4] = {0.f, 0.f, 0.f, 0.f};
        for (int ksl = 0; ksl < splitK; ++ksl) {
            const float4 pv =
                *(const float4*)&P[((size_t)ksl * TDIM + tok) * EDIM + lane * 4];
            a[0] += pv.x; a[1] += pv.y; a[2] += pv.z; a[3] += pv.w;
        }
        float v[4], s[4];
#pragma unroll
        for (int jq = 0; jq < 4; ++jq) {
            v[jq] = 1.f / (1.f + expf(-a[jq]));
            s[jq] = v[jq] + bb[jq];
        }
        float t1 = s[0], t2 = -FLT_MAX;
#pragma unroll
        for (int jq = 1; jq < 4; ++jq) {
            if (s[jq] > t1) { t2 = t1; t1 = s[jq]; }
            else if (s[jq] > t2) t2 = s[jq];
        }
#pragma unroll
        for (int d = 1; d < 8; d <<= 1) {
            float o1 = __shfl_xor(t1, d);
            float o2 = __shfl_xor(t2, d);
            float n1 = fmaxf(t1, o1);
            float n2 = fmaxf(fminf(t1, o1), fmaxf(t2, o2));
            t1 = n1; t2 = n2;
        }
        const float gsc = t1 + t2;
        float gs[8];
#pragma unroll
        for (int q = 0; q < 8; ++q) gs[q] = __shfl(gsc, q * 8);
        int gmask = 0;
#pragma unroll
        for (int it = 0; it < 4; ++it) {
            float bvv = -FLT_MAX; int bg = 0;
#pragma unroll
            for (int q = 0; q < 8; ++q) {
                const bool avail = ((gmask >> q) & 1) == 0;
                if (avail && gs[q] > bvv) { bvv = gs[q]; bg = q; }
            }
            gmask |= (1 << bg);
        }
        if (((gmask >> g) & 1) == 0) { s[0] = 0.f; s[1] = 0.f; s[2] = 0.f; s[3] = 0.f; }

        float wk[8]; int ik[8]; float wsum = 0.f;
#pragma unroll
        for (int it = 0; it < 8; ++it) {
            float bvv = s[0]; int bi = lane * 4; float bs = v[0];
#pragma unroll
            for (int jq = 1; jq < 4; ++jq)
                if (s[jq] > bvv) { bvv = s[jq]; bi = lane * 4 + jq; bs = v[jq]; }
#pragma unroll
            for (int d = 1; d < 64; d <<= 1) {
                float ov = __shfl_xor(bvv, d);
                int   oi = __shfl_xor(bi, d);
                float os = __shfl_xor(bs, d);
                if (ov > bvv || (ov == bvv && oi < bi)) { bvv = ov; bi = oi; bs = os; }
            }
            wk[it] = bs; ik[it] = bi; wsum += bs;
#pragma unroll
            for (int jq = 0; jq < 4; ++jq)
                if (bi == lane * 4 + jq) s[jq] = -FLT_MAX;
        }
        const float den = wsum + 1e-20f;
        if (lane == 0) {
#pragma unroll
            for (int q = 0; q < 8; ++q) {
                out[(size_t)tok * 8 + q] = wk[q] / den * 2.5f;
                out[(size_t)TDIM * 8 + (size_t)tok * 8 + q] = (float)ik[q];
            }
        }
    }
}

extern "C" void kernel_launch(void* const* d_in, const int* in_sizes, int n_in,
                              void* d_out, int out_size, void* d_ws, size_t ws_size,
                              hipStream_t stream)
{
    (void)in_sizes; (void)n_in; (void)out_size;
    const float* x    = (const float*)d_in[0];
    const float* kern = (const float*)d_in[1];
    const float* bias = (const float*)d_in[2];
    float* out = (float*)d_out;

    const size_t packedBytes = (size_t)2 * PSTR * 2;   // 7.34 MB (2 planes)
    int splitK = 4;
    while (splitK > 1 &&
           (size_t)splitK * TDIM * EDIM * 4 + packedBytes > ws_size)
        splitK >>= 1;

    float* P = (float*)d_ws;
    short* Bp = (short*)((char*)d_ws + (size_t)splitK * TDIM * EDIM * 4);

    convert_w<<<dim3(DDIM / 64, EDIM / 64), 256, 0, stream>>>(kern, Bp);
    gemm_mfma<<<(TDIM / 64) * splitK, 256, 0, stream>>>(
        x, Bp, P, splitK, DDIM / splitK);
    route_kernel<<<TDIM / 32, 256, 0, stream>>>(P, bias, out, splitK);
}

// Round 17
// 177.654 us; speedup vs baseline: 2.9619x; 2.9619x over previous
//
#include <hip/hip_runtime.h>
#include <math.h>
#include <float.h>

// DeepSeek V3 router, round 17.
// R16 post-mortem: bf16-derive path spills (cvt temp pressure) - abandoned.
// Back to the VALIDATED R9 line. New pipe model: R9's limiter was B-feed
// (32KB/block-tile from L2 = 1170cy > matrix 775cy). R17 = R9 skeleton with
// block 128Mx128N (4 waves, 2Mx2N wave grid, wave-tile 64x64): B per
// block-tile halves per-flop (16KB = 292cy < matrix 775cy). N=128 -> the two
// N-blocks sharing an X slice are XCD-paired (R5's chunked remap) so the
// second X read hits L2/L3 (X=235MB fits the 256MB L3).
// Numerics/staging/swizzle/packing verbatim from validated R9/R11/R13:
//   pass1 a0*b0; RB*=S5; a1*=S6; pass2 a1*b0s; a0*=S5; pass3 a0s*b3;
//   a0=fp16(x), a1=fp16(res_x*2048), b0=fp16(256w), b3=fp16(res_w256*32);
//   logit = acc/256.

#define TDIM 8192
#define DDIM 7168
#define EDIM 256
#define KT   (DDIM / 32)   // 224 k-tiles of 32

typedef _Float16 h8 __attribute__((ext_vector_type(8)));
typedef float  f16v __attribute__((ext_vector_type(16)));

// ---------------- K1: W -> 32x32x16-fragment-packed fp16 planes ------------
// (verbatim R9, validated) Offset(halfs) = (((p*8+cf)*KT+ktl)*2+kf)*512
// + lane*8, lane = (e&31) + 32*((k>>3)&1).
__global__ __launch_bounds__(256)
void convert_w(const float* __restrict__ W, _Float16* __restrict__ Bp)
{
    __shared__ _Float16 l0[64][80];
    __shared__ _Float16 l1[64][80];
    const int t = threadIdx.x;
    const int kt = blockIdx.x * 64;
    const int et = blockIdx.y * 64;
#pragma unroll
    for (int i = 0; i < 16; ++i) {
        const int kr = (t >> 6) * 16 + i;
        const int ec = t & 63;
        const float w = W[(size_t)(kt + kr) * EDIM + et + ec] * 256.f;
        const _Float16 h0 = (_Float16)w;
        const _Float16 h1 = (_Float16)((w - (float)h0) * 32.f);
        l0[ec][kr] = h0;
        l1[ec][kr] = h1;
    }
    __syncthreads();
#pragma unroll
    for (int j = 0; j < 2; ++j) {
        const int er = t >> 2;
        const int kc = ((t & 3) + 4 * j) * 8;
        const int e  = et + er;
        const int k  = kt + kc;
        const int cf   = e >> 5;
        const int lane = (e & 31) + 32 * ((k >> 3) & 1);
        const int kf   = (k >> 4) & 1;
        const int ktl  = k >> 5;
        const uint4 v0 = *(const uint4*)&l0[er][kc];
        const uint4 v1 = *(const uint4*)&l1[er][kc];
        const size_t o0 = (((size_t)(0 * 8 + cf) * KT + ktl) * 2 + kf) * 512 + lane * 8;
        const size_t o1 = (((size_t)(1 * 8 + cf) * KT + ktl) * 2 + kf) * 512 + lane * 8;
        *(uint4*)&Bp[o0] = v0;
        *(uint4*)&Bp[o1] = v1;
    }
}

// ---- K2: 32x32x16 split-fp16 GEMM, 128Mx128N block, A LDS / B from L2 -----
__global__ __launch_bounds__(256, 2)
void gemm_mfma(const float* __restrict__ X,
               const _Float16* __restrict__ Bp,
               float* __restrict__ P,
               int splitK, int kLen)
{
    __shared__ _Float16 sA[2][2][128][32];  // 32 KB: [buf][plane][row][halfs]

    const int t    = threadIdx.x;
    const int lane = t & 63;
    const int w    = t >> 6;                // wave: (w>>1)=M half, (w&1)=N half

    // XCD-chunked remap (R5-validated): nb pairs sharing X land on one XCD.
    const int cpx = gridDim.x >> 3;
    const int L   = (blockIdx.x & 7) * cpx + (blockIdx.x >> 3);
    const int nb  = L & 1;
    const int r1  = L >> 1;
    const int ks  = r1 % splitK;
    const int mb  = r1 / splitK;
    const int m0  = mb * 128;
    const int kbeg = ks * kLen;
    const int nt   = kLen >> 5;             // 56 steps
    const int ktg0 = kbeg >> 5;

    f16v acc[2][2];
#pragma unroll
    for (int m = 0; m < 2; ++m)
#pragma unroll
        for (int n = 0; n < 2; ++n) acc[m][n] = (f16v)0.f;

    // A staging: thread -> row t>>1 (0..127), slots (t&1) and (t&1)+2
    const int rowA = t >> 1;
    const int gA0  = t & 1;
    const float* xg = X + (size_t)(m0 + rowA) * DDIM + kbeg + gA0 * 8;
    const int slot0 = (gA0 ^ ((rowA >> 2) & 3)) * 8;
    const int slot1 = ((gA0 + 2) ^ ((rowA >> 2) & 3)) * 8;

    const _Float16* bbase = Bp + lane * 8;

    float4 va0, va1, va2, va3;

#define LOADA(kb)                                                             \
    {                                                                         \
        va0 = *(const float4*)(xg + (kb));                                    \
        va1 = *(const float4*)(xg + (kb) + 4);                                \
        va2 = *(const float4*)(xg + (kb) + 16);                               \
        va3 = *(const float4*)(xg + (kb) + 20);                               \
    }

#define CONV8(P0, P1, R0, R1)                                                 \
    {                                                                         \
        const float xv[8] = {R0.x, R0.y, R0.z, R0.w,                          \
                             R1.x, R1.y, R1.z, R1.w};                         \
        _Pragma("unroll")                                                     \
        for (int q = 0; q < 8; ++q) {                                         \
            const _Float16 h0 = (_Float16)xv[q];                              \
            P0[q] = h0;                                                       \
            P1[q] = (_Float16)((xv[q] - (float)h0) * 2048.f);                 \
        }                                                                     \
    }

#define WRITEA(buf)                                                           \
    {                                                                         \
        h8 p0, p1, p2, p3;                                                    \
        CONV8(p0, p1, va0, va1);                                              \
        CONV8(p2, p3, va2, va3);                                              \
        *(h8*)&sA[buf][0][rowA][slot0] = p0;                                  \
        *(h8*)&sA[buf][1][rowA][slot0] = p1;                                  \
        *(h8*)&sA[buf][0][rowA][slot1] = p2;                                  \
        *(h8*)&sA[buf][1][rowA][slot1] = p3;                                  \
    }

    // B frag set: cf = nb*4 + (w&1)*2 + n
#define BLOAD(RB, TI)                                                         \
    {                                                                         \
        _Pragma("unroll")                                                     \
        for (int p = 0; p < 2; ++p)                                           \
        _Pragma("unroll")                                                     \
        for (int n = 0; n < 2; ++n)                                           \
        _Pragma("unroll")                                                     \
        for (int kf = 0; kf < 2; ++kf)                                        \
            RB[p][n][kf] = *(const h8*)(bbase +                               \
                (((size_t)(p * 8 + nb * 4 + (w & 1) * 2 + n) * KT +           \
                  ktg0 + (TI)) * 2 + kf) * 512);                              \
    }

#define AREAD(CUR)                                                            \
    {                                                                         \
        _Pragma("unroll")                                                     \
        for (int m = 0; m < 2; ++m)                                           \
        _Pragma("unroll")                                                     \
        for (int kf = 0; kf < 2; ++kf) {                                      \
            const int rr = (w >> 1) * 64 + m * 32 + (lane & 31);              \
            const int sl = (((lane >> 5) + 2 * kf) ^ ((rr >> 2) & 3)) * 8;    \
            a0[m][kf] = *(const h8*)&sA[CUR][0][rr][sl];                      \
            a1[m][kf] = *(const h8*)&sA[CUR][1][rr][sl];                      \
        }                                                                     \
    }

    // validated MFMA3 (R9): in-place scaling AFTER all consumers of each pass
#define MFMA3(RB)                                                             \
    {                                                                         \
        __builtin_amdgcn_s_setprio(1);                                        \
        _Pragma("unroll")                                                     \
        for (int m = 0; m < 2; ++m)                                           \
        _Pragma("unroll")                                                     \
        for (int n = 0; n < 2; ++n)                                           \
        _Pragma("unroll")                                                     \
        for (int kf = 0; kf < 2; ++kf)                                        \
            acc[m][n] = __builtin_amdgcn_mfma_f32_32x32x16_f16(               \
                a0[m][kf], RB[0][n][kf], acc[m][n], 0, 0, 0);                 \
        _Pragma("unroll")                                                     \
        for (int n = 0; n < 2; ++n)                                           \
        _Pragma("unroll")                                                     \
        for (int kf = 0; kf < 2; ++kf)                                        \
        _Pragma("unroll")                                                     \
        for (int q = 0; q < 8; ++q) RB[0][n][kf][q] *= S5;                    \
        _Pragma("unroll")                                                     \
        for (int m = 0; m < 2; ++m)                                           \
        _Pragma("unroll")                                                     \
        for (int kf = 0; kf < 2; ++kf)                                        \
        _Pragma("unroll")                                                     \
        for (int q = 0; q < 8; ++q) a1[m][kf][q] *= S6;                       \
        _Pragma("unroll")                                                     \
        for (int m = 0; m < 2; ++m)                                           \
        _Pragma("unroll")                                                     \
        for (int n = 0; n < 2; ++n)                                           \
        _Pragma("unroll")                                                     \
        for (int kf = 0; kf < 2; ++kf)                                        \
            acc[m][n] = __builtin_amdgcn_mfma_f32_32x32x16_f16(               \
                a1[m][kf], RB[0][n][kf], acc[m][n], 0, 0, 0);                 \
        _Pragma("unroll")                                                     \
        for (int m = 0; m < 2; ++m)                                           \
        _Pragma("unroll")                                                     \
        for (int kf = 0; kf < 2; ++kf)                                        \
        _Pragma("unroll")                                                     \
        for (int q = 0; q < 8; ++q) a0[m][kf][q] *= S5;                       \
        _Pragma("unroll")                                                     \
        for (int m = 0; m < 2; ++m)                                           \
        _Pragma("unroll")                                                     \
        for (int n = 0; n < 2; ++n)                                           \
        _Pragma("unroll")                                                     \
        for (int kf = 0; kf < 2; ++kf)                                        \
            acc[m][n] = __builtin_amdgcn_mfma_f32_32x32x16_f16(               \
                a0[m][kf], RB[1][n][kf], acc[m][n], 0, 0, 0);                 \
        __builtin_amdgcn_s_setprio(0);                                        \
    }

    const _Float16 S5 = (_Float16)0.03125f;     // 2^-5
    const _Float16 S6 = (_Float16)0.015625f;    // 2^-6

    h8 bE[2][2][2], bO[2][2][2];

    // ---- prologue: A(0)->buf0; B(0)->E ----
    LOADA(0);
    BLOAD(bE, 0);
    WRITEA(0);
    asm volatile("s_waitcnt lgkmcnt(0)" ::: "memory");
    __builtin_amdgcn_s_barrier();

    for (int ti = 0; ti < nt; ti += 2) {
        {   // even: tile ti from sA[0], bE
            h8 a0[2][2], a1[2][2];
            const bool hn = (ti + 1) < nt;
            if (hn) { LOADA((ti + 1) * 32); BLOAD(bO, ti + 1); }
            AREAD(0);
            MFMA3(bE);
            if (hn) WRITEA(1);
            asm volatile("s_waitcnt lgkmcnt(0)" ::: "memory");
            __builtin_amdgcn_s_barrier();
        }
        {   // odd: tile ti+1 from sA[1], bO
            h8 a0[2][2], a1[2][2];
            const bool hn = (ti + 2) < nt;
            if (hn) { LOADA((ti + 2) * 32); BLOAD(bE, ti + 2); }
            if (ti + 1 < nt) {
                AREAD(1);
                MFMA3(bO);
            }
            if (hn) WRITEA(0);
            asm volatile("s_waitcnt lgkmcnt(0)" ::: "memory");
            __builtin_amdgcn_s_barrier();
        }
    }

    // epilogue: logit = acc/256; C/D col=lane&31, row=(r&3)+8*(r>>2)+4*(lane>>5)
    const float s0 = 1.f / 256.f;
#pragma unroll
    for (int m = 0; m < 2; ++m)
#pragma unroll
        for (int n = 0; n < 2; ++n)
#pragma unroll
            for (int r = 0; r < 16; ++r) {
                const int row = (r & 3) + 8 * (r >> 2) + 4 * (lane >> 5);
                const int gr  = m0 + (w >> 1) * 64 + m * 32 + row;
                const int gc  = nb * 128 + (w & 1) * 64 + n * 32 + (lane & 31);
                P[((size_t)ks * TDIM + gr) * EDIM + gc] = acc[m][n][r] * s0;
            }
}

// ---------------- K3: reduce + sigmoid + grouped top-k route ----------------
__global__ __launch_bounds__(256, 4)
void route_kernel(const float* __restrict__ P,
                  const float* __restrict__ B,
                  float* __restrict__ out,
                  int splitK)
{
    const int t    = threadIdx.x;
    const int lane = t & 63;
    const int wid  = t >> 6;
    const int tok0 = blockIdx.x * 32 + wid * 8;

    const float4 bv4 = *(const float4*)&B[lane * 4];
    const float bb[4] = {bv4.x, bv4.y, bv4.z, bv4.w};
    const int g = lane >> 3;

#pragma unroll
    for (int i = 0; i < 8; ++i) {
        const int tok = tok0 + i;
        float a[4] = {0.f, 0.f, 0.f, 0.f};
        for (int ksl = 0; ksl < splitK; ++ksl) {
            const float4 pv =
                *(const float4*)&P[((size_t)ksl * TDIM + tok) * EDIM + lane * 4];
            a[0] += pv.x; a[1] += pv.y; a[2] += pv.z; a[3] += pv.w;
        }
        float v[4], s[4];
#pragma unroll
        for (int jq = 0; jq < 4; ++jq) {
            v[jq] = 1.f / (1.f + expf(-a[jq]));
            s[jq] = v[jq] + bb[jq];
        }
        float t1 = s[0], t2 = -FLT_MAX;
#pragma unroll
        for (int jq = 1; jq < 4; ++jq) {
            if (s[jq] > t1) { t2 = t1; t1 = s[jq]; }
            else if (s[jq] > t2) t2 = s[jq];
        }
#pragma unroll
        for (int d = 1; d < 8; d <<= 1) {
            float o1 = __shfl_xor(t1, d);
            float o2 = __shfl_xor(t2, d);
            float n1 = fmaxf(t1, o1);
            float n2 = fmaxf(fminf(t1, o1), fmaxf(t2, o2));
            t1 = n1; t2 = n2;
        }
        const float gsc = t1 + t2;
        float gs[8];
#pragma unroll
        for (int q = 0; q < 8; ++q) gs[q] = __shfl(gsc, q * 8);
        int gmask = 0;
#pragma unroll
        for (int it = 0; it < 4; ++it) {
            float bvv = -FLT_MAX; int bg = 0;
#pragma unroll
            for (int q = 0; q < 8; ++q) {
                const bool avail = ((gmask >> q) & 1) == 0;
                if (avail && gs[q] > bvv) { bvv = gs[q]; bg = q; }
            }
            gmask |= (1 << bg);
        }
        if (((gmask >> g) & 1) == 0) { s[0] = 0.f; s[1] = 0.f; s[2] = 0.f; s[3] = 0.f; }

        float wk[8]; int ik[8]; float wsum = 0.f;
#pragma unroll
        for (int it = 0; it < 8; ++it) {
            float bvv = s[0]; int bi = lane * 4; float bs = v[0];
#pragma unroll
            for (int jq = 1; jq < 4; ++jq)
                if (s[jq] > bvv) { bvv = s[jq]; bi = lane * 4 + jq; bs = v[jq]; }
#pragma unroll
            for (int d = 1; d < 64; d <<= 1) {
                float ov = __shfl_xor(bvv, d);
                int   oi = __shfl_xor(bi, d);
                float os = __shfl_xor(bs, d);
                if (ov > bvv || (ov == bvv && oi < bi)) { bvv = ov; bi = oi; bs = os; }
            }
            wk[it] = bs; ik[it] = bi; wsum += bs;
#pragma unroll
            for (int jq = 0; jq < 4; ++jq)
                if (bi == lane * 4 + jq) s[jq] = -FLT_MAX;
        }
        const float den = wsum + 1e-20f;
        if (lane == 0) {
#pragma unroll
            for (int q = 0; q < 8; ++q) {
                out[(size_t)tok * 8 + q] = wk[q] / den * 2.5f;
                out[(size_t)TDIM * 8 + (size_t)tok * 8 + q] = (float)ik[q];
            }
        }
    }
}

extern "C" void kernel_launch(void* const* d_in, const int* in_sizes, int n_in,
                              void* d_out, int out_size, void* d_ws, size_t ws_size,
                              hipStream_t stream)
{
    (void)in_sizes; (void)n_in; (void)out_size;
    const float* x    = (const float*)d_in[0];
    const float* kern = (const float*)d_in[1];
    const float* bias = (const float*)d_in[2];
    float* out = (float*)d_out;

    const size_t packedBytes = (size_t)2 * 8 * KT * 2 * 512 * 2;   // 7.34 MB
    int splitK = 4;
    while (splitK > 1 &&
           (size_t)splitK * TDIM * EDIM * 4 + packedBytes > ws_size)
        splitK >>= 1;

    float* P = (float*)d_ws;
    _Float16* Bp = (_Float16*)((char*)d_ws + (size_t)splitK * TDIM * EDIM * 4);

    convert_w<<<dim3(DDIM / 64, EDIM / 64), 256, 0, stream>>>(kern, Bp);
    gemm_mfma<<<(TDIM / 128) * 2 * splitK, 256, 0, stream>>>(
        x, Bp, P, splitK, DDIM / splitK);
    route_kernel<<<TDIM / 32, 256, 0, stream>>>(P, bias, out, splitK);
}